// Round 1
// baseline (346.086 us; speedup 1.0000x reference)
//
#include <hip/hip_runtime.h>
#include <math.h>

#define NSM 4
#define NCELL 64
#define NREP 64
#define RSTRIDE 65   // +1 pad so replica r of cell c lands in bank (r+c)%32

// ---------- helpers ----------

__device__ __forceinline__ void inv3x3(const float* __restrict__ C, float* inv) {
    float a=C[0],b=C[1],c=C[2],d=C[3],e=C[4],f=C[5],g=C[6],h=C[7],i=C[8];
    float A  =  (e*i - f*h);
    float B  = -(d*i - f*g);
    float Cc =  (d*h - e*g);
    float det = a*A + b*B + c*Cc;
    float rd = 1.0f/det;
    inv[0] = A*rd;
    inv[1] = (c*h - b*i)*rd;
    inv[2] = (b*f - c*e)*rd;
    inv[3] = B*rd;
    inv[4] = (a*i - c*g)*rd;
    inv[5] = (c*d - a*f)*rd;
    inv[6] = Cc*rd;
    inv[7] = (b*g - a*h)*rd;
    inv[8] = (a*e - b*d)*rd;
}

struct Stencil {
    float wx[3], wy[3], wz[3];
    int   ix[3], iy[3], iz[3];
};

__device__ __forceinline__ void make_axis(float u, float* w, int* idx) {
    float nf = floorf(u + 0.5f);
    float x  = u - nf;           // in [-0.5, 0.5]
    w[0] = 0.5f*(0.5f - x)*(0.5f - x);
    w[1] = 0.75f - x*x;
    w[2] = 0.5f*(0.5f + x)*(0.5f + x);
    int n0 = (int)nf;            // 0..4 for in-box positions
    idx[0] = (n0 + 3) & 3;
    idx[1] =  n0      & 3;
    idx[2] = (n0 + 1) & 3;
}

__device__ __forceinline__ void make_stencil(float px, float py, float pz,
                                             const float* ci, Stencil& s) {
    // frac_j = sum_i p_i * Cinv[i][j]
    float fx = px*ci[0] + py*ci[3] + pz*ci[6];
    float fy = px*ci[1] + py*ci[4] + pz*ci[7];
    float fz = px*ci[2] + py*ci[5] + pz*ci[8];
    make_axis(fx*(float)NSM, s.wx, s.ix);
    make_axis(fy*(float)NSM, s.wy, s.iy);
    make_axis(fz*(float)NSM, s.wz, s.iz);
}

__device__ __forceinline__ float fast_tanh(float x) {
    float ax = fabsf(x);
    float e  = __expf(-2.0f*ax);            // in (0,1], never overflows
    float t  = __fdividef(1.0f - e, 1.0f + e);
    return copysignf(t, x);
}

// ---------- kernel A: scatter charges to 64-cell mesh ----------

__global__ __launch_bounds__(256) void scatter_kernel(
        const float* __restrict__ pos, const float* __restrict__ cell,
        const float* __restrict__ charges, float* __restrict__ mesh_out, int N) {
    __shared__ float lmesh[NREP * RSTRIDE];
    for (int t = threadIdx.x; t < NREP * RSTRIDE; t += blockDim.x) lmesh[t] = 0.0f;
    float ci[9]; inv3x3(cell, ci);
    __syncthreads();

    const int rep_base = (threadIdx.x & 63) * RSTRIDE; // lane-private replica
    int tid    = blockIdx.x * blockDim.x + threadIdx.x;
    int stride = gridDim.x * blockDim.x;

    for (int n = tid; n < N; n += stride) {
        float px = pos[3*n], py = pos[3*n+1], pz = pos[3*n+2];
        float q  = charges[n];
        Stencil s; make_stencil(px, py, pz, ci, s);
        #pragma unroll
        for (int a = 0; a < 3; a++) {
            float wa = s.wx[a] * q;
            int   ia = rep_base + s.ix[a]*16;
            #pragma unroll
            for (int b = 0; b < 3; b++) {
                float wab = wa * s.wy[b];
                int   iab = ia + s.iy[b]*4;
                #pragma unroll
                for (int c = 0; c < 3; c++) {
                    atomicAdd(&lmesh[iab + s.iz[c]], wab * s.wz[c]);
                }
            }
        }
    }
    __syncthreads();
    if (threadIdx.x < NCELL) {
        float sum = 0.0f;
        #pragma unroll 8
        for (int r = 0; r < NREP; r++) sum += lmesh[r*RSTRIDE + threadIdx.x];
        atomicAdd(&mesh_out[threadIdx.x], sum);
    }
}

// ---------- kernel B: k-space filter as real circular convolution ----------
// mesh'[r] = sum_{r'} G[(r-r') mod 4] mesh[r'],
// G[D] = sum_{k full grid, k!=0} exp(-|k|^2 s2/2)/|k|^2 * cos(pi/2 * (a*Dx+b*Dy+c*Dz))
// (backward-norm rfft + forward-norm irfft => no 1/64 factor)

__global__ void filter_kernel(const float* __restrict__ cell,
                              const float* __restrict__ sigma2p,
                              const float* __restrict__ mesh_in,
                              float* __restrict__ mesh_out) {
    __shared__ float gr[64];
    __shared__ float mm[64];
    int t = threadIdx.x;            // 0..63
    float ci[9]; inv3x3(cell, ci);
    float s2 = sigma2p[0];
    const float twopi = 6.2831853071795864769f;
    // reciprocal rows: G_row[r] = 2*pi * column r of Cinv
    float G0x = twopi*ci[0], G0y = twopi*ci[3], G0z = twopi*ci[6];
    float G1x = twopi*ci[1], G1y = twopi*ci[4], G1z = twopi*ci[7];
    float G2x = twopi*ci[2], G2y = twopi*ci[5], G2z = twopi*ci[8];

    mm[t] = mesh_in[t];
    int dx = t >> 4, dy = (t >> 2) & 3, dz = t & 3;
    float acc = 0.0f;
    for (int a = 0; a < 4; a++) {
        float fa = (a < 2) ? (float)a : (float)(a - 4);
        for (int b = 0; b < 4; b++) {
            float fb = (b < 2) ? (float)b : (float)(b - 4);
            for (int c = 0; c < 4; c++) {
                if ((a | b | c) == 0) continue;
                float fc = (c < 2) ? (float)c : (float)(c - 4);
                float kx = fa*G0x + fb*G1x + fc*G2x;
                float ky = fa*G0y + fb*G1y + fc*G2y;
                float kz = fa*G0z + fb*G1z + fc*G2z;
                float k2 = kx*kx + ky*ky + kz*kz;
                float K  = expf(-k2 * s2 * 0.5f) / k2;
                int ph = (a*dx + b*dy + c*dz) & 3;
                float cs = (ph == 0) ? 1.0f : ((ph == 2) ? -1.0f : 0.0f);
                acc += K * cs;
            }
        }
    }
    gr[t] = acc;
    __syncthreads();
    float o = 0.0f;
    for (int s = 0; s < 64; s++) {
        int sx = s >> 4, sy = (s >> 2) & 3, sz = s & 3;
        int d = ((dx - sx) & 3)*16 + ((dy - sy) & 3)*4 + ((dz - sz) & 3);
        o += gr[d] * mm[s];
    }
    mesh_out[t] = o;
}

// ---------- kernel C: gather potential + MLP + global sum ----------

__global__ __launch_bounds__(256, 2) void gather_mlp_kernel(
        const float* __restrict__ pos, const float* __restrict__ cell,
        const float* __restrict__ charges,
        const float* __restrict__ W1, const float* __restrict__ b1,
        const float* __restrict__ W2, const float* __restrict__ b2,
        const float* __restrict__ W3, const float* __restrict__ b3,
        const float* __restrict__ meshf, float* __restrict__ out, int N) {
    __shared__ float mf[64];
    __shared__ float wavesum[4];
    if (threadIdx.x < 64) mf[threadIdx.x] = meshf[threadIdx.x];
    float ci[9]; inv3x3(cell, ci);

    // hoist all MLP weights into registers (uniform -> mostly SGPRs)
    float w1r0[10], w1r1[10], b1r[10], w2r[10][10], b2r[10], w3r[10];
    #pragma unroll
    for (int j = 0; j < 10; j++) {
        w1r0[j] = W1[j]; w1r1[j] = W1[10 + j];
        b1r[j] = b1[j];  b2r[j] = b2[j]; w3r[j] = W3[j];
    }
    #pragma unroll
    for (int i = 0; i < 10; i++) {
        #pragma unroll
        for (int j = 0; j < 10; j++) w2r[i][j] = W2[10*i + j];
    }
    float b3r = b3[0];
    __syncthreads();

    int tid    = blockIdx.x * blockDim.x + threadIdx.x;
    int stride = gridDim.x * blockDim.x;
    float ysum = 0.0f;

    for (int n = tid; n < N; n += stride) {
        float px = pos[3*n], py = pos[3*n+1], pz = pos[3*n+2];
        float q  = charges[n];
        Stencil s; make_stencil(px, py, pz, ci, s);

        float pot = 0.0f;
        #pragma unroll
        for (int a = 0; a < 3; a++) {
            int ia = s.ix[a]*16;
            #pragma unroll
            for (int b = 0; b < 3; b++) {
                float wab = s.wx[a]*s.wy[b];
                int iab = ia + s.iy[b]*4;
                #pragma unroll
                for (int c = 0; c < 3; c++)
                    pot += wab * s.wz[c] * mf[iab + s.iz[c]];
            }
        }

        float h1[10], h2[10];
        #pragma unroll
        for (int j = 0; j < 10; j++)
            h1[j] = fast_tanh(q*w1r0[j] + pot*w1r1[j] + b1r[j]);
        #pragma unroll
        for (int j = 0; j < 10; j++) {
            float acc = b2r[j];
            #pragma unroll
            for (int i = 0; i < 10; i++) acc += h1[i]*w2r[i][j];
            h2[j] = fast_tanh(acc);
        }
        float y = b3r;
        #pragma unroll
        for (int j = 0; j < 10; j++) y += h2[j]*w3r[j];
        ysum += y;
    }

    // wave reduce (64 lanes)
    ysum += __shfl_down(ysum, 32);
    ysum += __shfl_down(ysum, 16);
    ysum += __shfl_down(ysum, 8);
    ysum += __shfl_down(ysum, 4);
    ysum += __shfl_down(ysum, 2);
    ysum += __shfl_down(ysum, 1);
    int wid  = threadIdx.x >> 6;
    int lane = threadIdx.x & 63;
    if (lane == 0) wavesum[wid] = ysum;
    __syncthreads();
    if (threadIdx.x == 0) {
        float tsum = wavesum[0] + wavesum[1] + wavesum[2] + wavesum[3];
        atomicAdd(out, tsum);
    }
}

// ---------- launch ----------

extern "C" void kernel_launch(void* const* d_in, const int* in_sizes, int n_in,
                              void* d_out, int out_size, void* d_ws, size_t ws_size,
                              hipStream_t stream) {
    const float* pos     = (const float*)d_in[0];
    const float* cell    = (const float*)d_in[1];
    const float* charges = (const float*)d_in[2];
    const float* sigma2  = (const float*)d_in[3];
    const float* W1 = (const float*)d_in[4];
    const float* b1 = (const float*)d_in[5];
    const float* W2 = (const float*)d_in[6];
    const float* b2 = (const float*)d_in[7];
    const float* W3 = (const float*)d_in[8];
    const float* b3 = (const float*)d_in[9];
    int N = in_sizes[2];                 // charges (N,1)

    float* mesh  = (float*)d_ws;         // 64 floats
    float* meshf = mesh + 64;            // 64 floats

    hipMemsetAsync(mesh, 0, NCELL*sizeof(float), stream);
    hipMemsetAsync(d_out, 0, out_size*sizeof(float), stream);

    scatter_kernel<<<1024, 256, 0, stream>>>(pos, cell, charges, mesh, N);
    filter_kernel<<<1, 64, 0, stream>>>(cell, sigma2, mesh, meshf);
    gather_mlp_kernel<<<2048, 256, 0, stream>>>(pos, cell, charges,
                                                W1, b1, W2, b2, W3, b3,
                                                meshf, (float*)d_out, N);
}

// Round 2
// 94.187 us; speedup vs baseline: 3.6745x; 3.6745x over previous
//
#include <hip/hip_runtime.h>
#include <math.h>

#define NSM 4
#define NCELL 64
#define SC_GRID 512
#define GA_GRID 1024

// ---------- helpers ----------

__device__ __forceinline__ void inv3x3(const float* __restrict__ C, float* inv) {
    float a=C[0],b=C[1],c=C[2],d=C[3],e=C[4],f=C[5],g=C[6],h=C[7],i=C[8];
    float A  =  (e*i - f*h);
    float B  = -(d*i - f*g);
    float Cc =  (d*h - e*g);
    float det = a*A + b*B + c*Cc;
    float rd = 1.0f/det;
    inv[0] = A*rd;
    inv[1] = (c*h - b*i)*rd;
    inv[2] = (b*f - c*e)*rd;
    inv[3] = B*rd;
    inv[4] = (a*i - c*g)*rd;
    inv[5] = (c*d - a*f)*rd;
    inv[6] = Cc*rd;
    inv[7] = (b*g - a*h)*rd;
    inv[8] = (a*e - b*d)*rd;
}

// M3 (order-3) B-spline weight of grid point j for scaled coord u, periodic in 4.
// w(t) = 0.5*max(1.5-|t|,0)^2 - 1.5*max(0.5-|t|,0)^2, t wrapped to [-2,2].
__device__ __forceinline__ void axis_weights4(float u, float* __restrict__ W) {
    #pragma unroll
    for (int j = 0; j < 4; j++) {
        float t = u - (float)j;
        float r = rintf(t * 0.25f);
        t = fmaf(r, -4.0f, t);
        float at = fabsf(t);
        float a = fmaxf(1.5f - at, 0.0f);
        float b = fmaxf(0.5f - at, 0.0f);
        W[j] = fmaf(0.5f*a, a, -1.5f*b*b);
    }
}

struct Stencil {
    float wx[3], wy[3], wz[3];
    int   ix[3], iy[3], iz[3];
};

__device__ __forceinline__ void make_axis(float u, float* w, int* idx) {
    float nf = floorf(u + 0.5f);
    float x  = u - nf;           // in [-0.5, 0.5]
    w[0] = 0.5f*(0.5f - x)*(0.5f - x);
    w[1] = 0.75f - x*x;
    w[2] = 0.5f*(0.5f + x)*(0.5f + x);
    int n0 = (int)nf;
    idx[0] = (n0 + 3) & 3;
    idx[1] =  n0      & 3;
    idx[2] = (n0 + 1) & 3;
}

__device__ __forceinline__ void make_stencil(float px, float py, float pz,
                                             const float* ci, Stencil& s) {
    float fx = px*ci[0] + py*ci[3] + pz*ci[6];
    float fy = px*ci[1] + py*ci[4] + pz*ci[7];
    float fz = px*ci[2] + py*ci[5] + pz*ci[8];
    make_axis(fx*(float)NSM, s.wx, s.ix);
    make_axis(fy*(float)NSM, s.wy, s.iy);
    make_axis(fz*(float)NSM, s.wz, s.iz);
}

__device__ __forceinline__ float fast_tanh(float x) {
    float ax = fabsf(x);
    float e  = __expf(-2.0f*ax);
    float t  = __fdividef(1.0f - e, 1.0f + e);
    return copysignf(t, x);
}

// ---------- kernel A: scatter via per-thread register mesh ----------

__global__ __launch_bounds__(256) void scatter_kernel(
        const float* __restrict__ pos, const float* __restrict__ cell,
        const float* __restrict__ charges, float* __restrict__ mesh_out, int N) {
    __shared__ float red[256 * 64];            // [t][c], c XOR-swizzled by (t&31); 64 KB
    float ci[9]; inv3x3(cell, ci);

    float macc[64];
    #pragma unroll
    for (int i = 0; i < 64; i++) macc[i] = 0.0f;

    int tid    = blockIdx.x * blockDim.x + threadIdx.x;
    int stride = gridDim.x * blockDim.x;

    for (int n = tid; n < N; n += stride) {
        float px = pos[3*n], py = pos[3*n+1], pz = pos[3*n+2];
        float q  = charges[n];
        float fx = px*ci[0] + py*ci[3] + pz*ci[6];
        float fy = px*ci[1] + py*ci[4] + pz*ci[7];
        float fz = px*ci[2] + py*ci[5] + pz*ci[8];
        float X[4], Y[4], Z[4];
        axis_weights4(fx*(float)NSM, X);
        axis_weights4(fy*(float)NSM, Y);
        axis_weights4(fz*(float)NSM, Z);
        float qX[4];
        #pragma unroll
        for (int x = 0; x < 4; x++) qX[x] = q * X[x];
        #pragma unroll
        for (int x = 0; x < 4; x++) {
            #pragma unroll
            for (int y = 0; y < 4; y++) {
                float wxy = qX[x] * Y[y];
                #pragma unroll
                for (int z = 0; z < 4; z++)
                    macc[x*16 + y*4 + z] = fmaf(wxy, Z[z], macc[x*16 + y*4 + z]);
            }
        }
    }

    // stage: thread t writes cell c at red[t*64 + (c ^ (t&31))] -> conflict-free
    int t  = threadIdx.x;
    int sw = t & 31;
    #pragma unroll
    for (int c = 0; c < 64; c++) red[t*64 + (c ^ sw)] = macc[c];
    __syncthreads();

    // reduce: thread t handles cell (t&63), source-group g=(t>>6) of 64 threads
    int cl = t & 63;
    int g  = t >> 6;
    float sum = 0.0f;
    #pragma unroll
    for (int i = 0; i < 64; i++) {
        int s = g*64 + i;                       // s&31 == i&31 (g*64 is mult of 32)
        sum += red[s*64 + (cl ^ (i & 31))];
    }
    __syncthreads();
    red[t] = sum;                               // reuse LDS: [g*64 + cl]
    __syncthreads();
    if (t < NCELL) {
        float v = red[t] + red[64 + t] + red[128 + t] + red[192 + t];
        unsafeAtomicAdd(&mesh_out[t], v);       // HW global_atomic_add_f32
    }
}

// ---------- kernel B: k-space filter as real circular convolution ----------
// (backward-norm rfft + forward-norm irfft => no 1/64 factor)

__global__ void filter_kernel(const float* __restrict__ cell,
                              const float* __restrict__ sigma2p,
                              const float* __restrict__ mesh_in,
                              float* __restrict__ mesh_out,
                              float* __restrict__ out_zero) {
    __shared__ float gr[64];
    __shared__ float mm[64];
    int t = threadIdx.x;            // 0..63
    float ci[9]; inv3x3(cell, ci);
    float s2 = sigma2p[0];
    const float twopi = 6.2831853071795864769f;
    float G0x = twopi*ci[0], G0y = twopi*ci[3], G0z = twopi*ci[6];
    float G1x = twopi*ci[1], G1y = twopi*ci[4], G1z = twopi*ci[7];
    float G2x = twopi*ci[2], G2y = twopi*ci[5], G2z = twopi*ci[8];

    mm[t] = mesh_in[t];
    int dx = t >> 4, dy = (t >> 2) & 3, dz = t & 3;
    float acc = 0.0f;
    for (int a = 0; a < 4; a++) {
        float fa = (a < 2) ? (float)a : (float)(a - 4);
        for (int b = 0; b < 4; b++) {
            float fb = (b < 2) ? (float)b : (float)(b - 4);
            for (int c = 0; c < 4; c++) {
                if ((a | b | c) == 0) continue;
                float fc = (c < 2) ? (float)c : (float)(c - 4);
                float kx = fa*G0x + fb*G1x + fc*G2x;
                float ky = fa*G0y + fb*G1y + fc*G2y;
                float kz = fa*G0z + fb*G1z + fc*G2z;
                float k2 = kx*kx + ky*ky + kz*kz;
                float K  = expf(-k2 * s2 * 0.5f) / k2;
                int ph = (a*dx + b*dy + c*dz) & 3;
                float cs = (ph == 0) ? 1.0f : ((ph == 2) ? -1.0f : 0.0f);
                acc += K * cs;
            }
        }
    }
    gr[t] = acc;
    __syncthreads();
    float o = 0.0f;
    for (int s = 0; s < 64; s++) {
        int sx = s >> 4, sy = (s >> 2) & 3, sz = s & 3;
        int d = ((dx - sx) & 3)*16 + ((dy - sy) & 3)*4 + ((dz - sz) & 3);
        o += gr[d] * mm[s];
    }
    mesh_out[t] = o;
    if (t == 0) out_zero[0] = 0.0f;   // zero the scalar output before gather adds
}

// ---------- kernel C: gather potential + MLP + global sum ----------

__global__ __launch_bounds__(256) void gather_mlp_kernel(
        const float* __restrict__ pos, const float* __restrict__ cell,
        const float* __restrict__ charges,
        const float* __restrict__ W1, const float* __restrict__ b1,
        const float* __restrict__ W2, const float* __restrict__ b2,
        const float* __restrict__ W3, const float* __restrict__ b3,
        const float* __restrict__ meshf, float* __restrict__ out, int N) {
    __shared__ float mf[64];
    __shared__ float wavesum[4];
    if (threadIdx.x < 64) mf[threadIdx.x] = meshf[threadIdx.x];
    float ci[9]; inv3x3(cell, ci);

    float w1r0[10], w1r1[10], b1r[10], w2r[10][10], b2r[10], w3r[10];
    #pragma unroll
    for (int j = 0; j < 10; j++) {
        w1r0[j] = W1[j]; w1r1[j] = W1[10 + j];
        b1r[j] = b1[j];  b2r[j] = b2[j]; w3r[j] = W3[j];
    }
    #pragma unroll
    for (int i = 0; i < 10; i++) {
        #pragma unroll
        for (int j = 0; j < 10; j++) w2r[i][j] = W2[10*i + j];
    }
    float b3r = b3[0];
    __syncthreads();

    int tid    = blockIdx.x * blockDim.x + threadIdx.x;
    int stride = gridDim.x * blockDim.x;
    float ysum = 0.0f;

    for (int n = tid; n < N; n += stride) {
        float px = pos[3*n], py = pos[3*n+1], pz = pos[3*n+2];
        float q  = charges[n];
        Stencil s; make_stencil(px, py, pz, ci, s);

        float pot = 0.0f;
        #pragma unroll
        for (int a = 0; a < 3; a++) {
            int ia = s.ix[a]*16;
            #pragma unroll
            for (int b = 0; b < 3; b++) {
                float wab = s.wx[a]*s.wy[b];
                int iab = ia + s.iy[b]*4;
                #pragma unroll
                for (int c = 0; c < 3; c++)
                    pot += wab * s.wz[c] * mf[iab + s.iz[c]];
            }
        }

        float h1[10], h2[10];
        #pragma unroll
        for (int j = 0; j < 10; j++)
            h1[j] = fast_tanh(q*w1r0[j] + pot*w1r1[j] + b1r[j]);
        #pragma unroll
        for (int j = 0; j < 10; j++) {
            float acc = b2r[j];
            #pragma unroll
            for (int i = 0; i < 10; i++) acc += h1[i]*w2r[i][j];
            h2[j] = fast_tanh(acc);
        }
        float y = b3r;
        #pragma unroll
        for (int j = 0; j < 10; j++) y += h2[j]*w3r[j];
        ysum += y;
    }

    // wave reduce (64 lanes)
    ysum += __shfl_down(ysum, 32);
    ysum += __shfl_down(ysum, 16);
    ysum += __shfl_down(ysum, 8);
    ysum += __shfl_down(ysum, 4);
    ysum += __shfl_down(ysum, 2);
    ysum += __shfl_down(ysum, 1);
    int wid  = threadIdx.x >> 6;
    int lane = threadIdx.x & 63;
    if (lane == 0) wavesum[wid] = ysum;
    __syncthreads();
    if (threadIdx.x == 0) {
        float tsum = wavesum[0] + wavesum[1] + wavesum[2] + wavesum[3];
        unsafeAtomicAdd(out, tsum);             // HW atomic, no CAS contention
    }
}

// ---------- launch ----------

extern "C" void kernel_launch(void* const* d_in, const int* in_sizes, int n_in,
                              void* d_out, int out_size, void* d_ws, size_t ws_size,
                              hipStream_t stream) {
    const float* pos     = (const float*)d_in[0];
    const float* cell    = (const float*)d_in[1];
    const float* charges = (const float*)d_in[2];
    const float* sigma2  = (const float*)d_in[3];
    const float* W1 = (const float*)d_in[4];
    const float* b1 = (const float*)d_in[5];
    const float* W2 = (const float*)d_in[6];
    const float* b2 = (const float*)d_in[7];
    const float* W3 = (const float*)d_in[8];
    const float* b3 = (const float*)d_in[9];
    int N = in_sizes[2];                 // charges (N,1)

    float* mesh  = (float*)d_ws;         // 64 floats
    float* meshf = mesh + 64;            // 64 floats

    hipMemsetAsync(mesh, 0, NCELL*sizeof(float), stream);

    scatter_kernel<<<SC_GRID, 256, 0, stream>>>(pos, cell, charges, mesh, N);
    filter_kernel<<<1, 64, 0, stream>>>(cell, sigma2, mesh, meshf, (float*)d_out);
    gather_mlp_kernel<<<GA_GRID, 256, 0, stream>>>(pos, cell, charges,
                                                   W1, b1, W2, b2, W3, b3,
                                                   meshf, (float*)d_out, N);
}